// Round 1
// baseline (231.237 us; speedup 1.0000x reference)
//
#include <hip/hip_runtime.h>
#include <hip/hip_bf16.h>
#include <cstdint>

#define Hh 16
#define Dd 1024
#define HD 64
#define Bb 2
#define Ss 2048

typedef float f32x4 __attribute__((ext_vector_type(4)));
typedef __bf16 bf16x8 __attribute__((ext_vector_type(8)));

__device__ __forceinline__ unsigned short f2bf(float f) {
  union { float f; unsigned u; } v; v.f = f;
  unsigned r = (v.u + 0x7FFFu + ((v.u >> 16) & 1u)) >> 16;  // RNE, finite inputs
  return (unsigned short)r;
}

__device__ __forceinline__ void gld16(const void* g, void* l) {
  __builtin_amdgcn_global_load_lds(
      (__attribute__((address_space(1))) void*)(g),
      (__attribute__((address_space(3))) void*)(l),
      16, 0, 0);
}

// ---------------------------------------------------------------------------
// Pack x (fp32 -> bf16), vectorized float4 -> ushort4
// ---------------------------------------------------------------------------
__global__ __launch_bounds__(256)
void pack_x_k(const float4* __restrict__ x, unsigned short* __restrict__ xb, int n4) {
  const int i = blockIdx.x * blockDim.x + threadIdx.x;
  if (i >= n4) return;
  const float4 v = x[i];
  ushort4 o;
  o.x = f2bf(v.x); o.y = f2bf(v.y); o.z = f2bf(v.z); o.w = f2bf(v.w);
  *(ushort4*)&xb[(size_t)i * 4] = o;
}

// ---------------------------------------------------------------------------
// Batched transpose + fp32->bf16: out[m][c][r] = in[m][r][c]
// grid: (C/64, R/64, nmat), block 256
// ---------------------------------------------------------------------------
__global__ __launch_bounds__(256)
void tconv_k(const float* __restrict__ in, unsigned short* __restrict__ out, int R, int C) {
  __shared__ float T[64][65];
  const int m = blockIdx.z;
  const float* src = in + (size_t)m * R * C;
  unsigned short* dst = out + (size_t)m * R * C;
  const int c0 = blockIdx.x * 64, r0 = blockIdx.y * 64;
  const int tx = threadIdx.x & 63, ty = threadIdx.x >> 6;
#pragma unroll
  for (int it = 0; it < 16; ++it) {
    const int i = ty + it * 4;
    T[i][tx] = src[(size_t)(r0 + i) * C + c0 + tx];
  }
  __syncthreads();
#pragma unroll
  for (int it = 0; it < 16; ++it) {
    const int jj = ty + it * 4;
    dst[(size_t)(c0 + jj) * R + r0 + tx] = f2bf(T[tx][jj]);
  }
}

// ---------------------------------------------------------------------------
// m97-style bf16 GEMM: A[M][K] row-major, Bt[N][K] row-major (= B^T).
// 128x128 tile, BK=64, 4 waves, 16x16x32 MFMA, global_load_lds width 16.
// EPI 0: QKV scatter (q,k as [bh][s][e] bf16; v transposed [bh][e][s] bf16)
// EPI 1: fp32 out + bias
// ---------------------------------------------------------------------------
template <int EPI>
__global__ __launch_bounds__(256)
void gemm_bt(const unsigned short* __restrict__ A,
             const unsigned short* __restrict__ Bt,
             int K, int Ndim,
             unsigned short* __restrict__ q_out,
             unsigned short* __restrict__ k_out,
             unsigned short* __restrict__ vt_out,
             float* __restrict__ o_out,
             const float* __restrict__ bias)
{
  __shared__ unsigned short As[128 * 64];
  __shared__ unsigned short Bs[128 * 64];

  const int tid = threadIdx.x;
  const int w = tid >> 6, lane = tid & 63;
  const int lo = lane & 15, hi = lane >> 4;
  const int wr = w >> 1, wc = w & 1;
  const int row0 = blockIdx.y * 128;
  const int col0 = blockIdx.x * 128;

  f32x4 acc[4][4] = {};

  const int er = w * 32 + (lane >> 3);   // staging row for c=0
  const int ec = (lane & 7) * 8;         // staging col (elements)

  for (int k0 = 0; k0 < K; k0 += 64) {
#pragma unroll
    for (int c = 0; c < 4; ++c) {
      const int rr = er + c * 8;
      gld16(A  + (size_t)(row0 + rr) * K + (k0 + ec), (char*)As + (size_t)(w * 4 + c) * 1024);
      gld16(Bt + (size_t)(col0 + rr) * K + (k0 + ec), (char*)Bs + (size_t)(w * 4 + c) * 1024);
    }
    __syncthreads();
#pragma unroll
    for (int ks = 0; ks < 2; ++ks) {
      bf16x8 af[4], bfr[4];
#pragma unroll
      for (int i = 0; i < 4; ++i)
        af[i] = *(const bf16x8*)&As[(wr * 64 + i * 16 + lo) * 64 + ks * 32 + hi * 8];
#pragma unroll
      for (int j = 0; j < 4; ++j)
        bfr[j] = *(const bf16x8*)&Bs[(wc * 64 + j * 16 + lo) * 64 + ks * 32 + hi * 8];
#pragma unroll
      for (int i = 0; i < 4; ++i)
#pragma unroll
        for (int j = 0; j < 4; ++j)
          acc[i][j] = __builtin_amdgcn_mfma_f32_16x16x32_bf16(af[i], bfr[j], acc[i][j], 0, 0, 0);
    }
    __syncthreads();
  }

#pragma unroll
  for (int i = 0; i < 4; ++i) {
    const int grow = row0 + wr * 64 + i * 16 + hi * 4;  // + r
#pragma unroll
    for (int j = 0; j < 4; ++j) {
      const int gcol = col0 + wc * 64 + j * 16 + lo;
      if (EPI == 0) {
        const int p  = gcol >> 10;
        const int hd = (gcol >> 6) & 15;
        const int e  = gcol & 63;
        const int bb2 = grow >> 11;
        const int s   = grow & 2047;
        const int bh  = bb2 * Hh + hd;
        if (p == 2) {
          const size_t base = ((size_t)bh * HD + e) * Ss + s;  // V^T: s contiguous over r
          ushort4 pk;
          pk.x = f2bf(acc[i][j][0]); pk.y = f2bf(acc[i][j][1]);
          pk.z = f2bf(acc[i][j][2]); pk.w = f2bf(acc[i][j][3]);
          *(ushort4*)&vt_out[base] = pk;
        } else {
          unsigned short* dst = (p == 0) ? q_out : k_out;
          const size_t base = ((size_t)bh * Ss + s) * HD + e;
#pragma unroll
          for (int r = 0; r < 4; ++r) dst[base + (size_t)r * HD] = f2bf(acc[i][j][r]);
        }
      } else {
        const size_t base = (size_t)grow * Ndim + gcol;
        const float bv = bias[gcol];
#pragma unroll
        for (int r = 0; r < 4; ++r) o_out[base + (size_t)r * Ndim] = acc[i][j][r] + bv;
      }
    }
  }
}

// ---------------------------------------------------------------------------
// Flash attention, causal. grid (S/128, B*H), 256 thr (4 waves x 32 q-rows).
// Q in registers; K tile [64 kk][64 e], V^T tile [64 e][64 kk] in LDS;
// online softmax wave-parallel over the 16-lane group; P via per-wave LDS.
// ---------------------------------------------------------------------------
__global__ __launch_bounds__(256)
void attn_fwd(const unsigned short* __restrict__ qb,
              const unsigned short* __restrict__ kb,
              const unsigned short* __restrict__ vtb,
              unsigned short* __restrict__ ob)
{
  __shared__ unsigned short Ks[64 * 64];
  __shared__ unsigned short Vs[64 * 64];
  __shared__ unsigned short Ps[4][32 * 64];

  const int qt = blockIdx.x;
  const int bh = blockIdx.y;
  const int bb2 = bh >> 4;
  const int hd = bh & 15;

  const unsigned short* Q  = qb  + (size_t)bh * Ss * HD;
  const unsigned short* Kg = kb  + (size_t)bh * Ss * HD;
  const unsigned short* Vt = vtb + (size_t)bh * HD * Ss;

  const int tid = threadIdx.x;
  const int w = tid >> 6, lane = tid & 63;
  const int lo = lane & 15, hi = lane >> 4;
  const int qrow0 = qt * 128 + w * 32;

  bf16x8 qf[2][2];
#pragma unroll
  for (int mi = 0; mi < 2; ++mi)
#pragma unroll
    for (int ks = 0; ks < 2; ++ks)
      qf[mi][ks] = *(const bf16x8*)&Q[(size_t)(qrow0 + mi * 16 + lo) * HD + ks * 32 + hi * 8];

  f32x4 oacc[2][4] = {};
  float mrun[2][4], lrun[2][4];
#pragma unroll
  for (int mi = 0; mi < 2; ++mi)
#pragma unroll
    for (int r = 0; r < 4; ++r) { mrun[mi][r] = -INFINITY; lrun[mi][r] = 0.f; }

  const int ntiles = qt * 2 + 2;          // causal: kk-tiles 0 .. qt*2+1
  const int stg_r = lane >> 3;
  const int stg_c = (lane & 7) * 8;

  for (int t = 0; t < ntiles; ++t) {
    const int kv0 = t * 64;
#pragma unroll
    for (int c = 0; c < 2; ++c) {
      const int eb = (w * 2 + c) * 512;   // element base of this wave-call
      gld16(Kg + (size_t)kv0 * HD + eb + lane * 8, (char*)Ks + (size_t)eb * 2);
      const int vrow = (eb >> 6) + stg_r;
      gld16(Vt + (size_t)vrow * Ss + kv0 + stg_c, (char*)Vs + (size_t)eb * 2);
    }
    __syncthreads();

    // S = Q K^T
    f32x4 sacc[2][4] = {};
#pragma unroll
    for (int ks = 0; ks < 2; ++ks) {
      bf16x8 kf[4];
#pragma unroll
      for (int nj = 0; nj < 4; ++nj)
        kf[nj] = *(const bf16x8*)&Ks[(nj * 16 + lo) * 64 + ks * 32 + hi * 8];
#pragma unroll
      for (int mi = 0; mi < 2; ++mi)
#pragma unroll
        for (int nj = 0; nj < 4; ++nj)
          sacc[mi][nj] = __builtin_amdgcn_mfma_f32_16x16x32_bf16(qf[mi][ks], kf[nj], sacc[mi][nj], 0, 0, 0);
    }

    // online softmax (row stats across the 16-lane group)
    float pp[2][4][4];
#pragma unroll
    for (int mi = 0; mi < 2; ++mi) {
#pragma unroll
      for (int r = 0; r < 4; ++r) {
        const int q = qrow0 + mi * 16 + hi * 4 + r;
        float sv[4];
        float rowmax = -INFINITY;
#pragma unroll
        for (int nj = 0; nj < 4; ++nj) {
          const int kk = kv0 + nj * 16 + lo;
          const float s = sacc[mi][nj][r] * 0.125f;
          sv[nj] = (kk <= q) ? s : -INFINITY;
          rowmax = fmaxf(rowmax, sv[nj]);
        }
#pragma unroll
        for (int d = 1; d < 16; d <<= 1)
          rowmax = fmaxf(rowmax, __shfl_xor(rowmax, d, 64));
        const float mnew = fmaxf(mrun[mi][r], rowmax);
        float rsum = 0.f;
#pragma unroll
        for (int nj = 0; nj < 4; ++nj) {
          const float p = __expf(sv[nj] - mnew);
          pp[mi][nj][r] = p;
          rsum += p;
        }
#pragma unroll
        for (int d = 1; d < 16; d <<= 1)
          rsum += __shfl_xor(rsum, d, 64);
        const float resc = __expf(mrun[mi][r] - mnew);
        lrun[mi][r] = lrun[mi][r] * resc + rsum;
        mrun[mi][r] = mnew;
#pragma unroll
        for (int nj = 0; nj < 4; ++nj)
          oacc[mi][nj][r] *= resc;
      }
    }

    // P -> per-wave LDS (reshape D-layout -> A-fragment layout)
    unsigned short* Pw = &Ps[w][0];
#pragma unroll
    for (int mi = 0; mi < 2; ++mi)
#pragma unroll
      for (int nj = 0; nj < 4; ++nj)
#pragma unroll
        for (int r = 0; r < 4; ++r)
          Pw[(mi * 16 + hi * 4 + r) * 64 + nj * 16 + lo] = f2bf(pp[mi][nj][r]);

    // O += P V
#pragma unroll
    for (int ks = 0; ks < 2; ++ks) {
      bf16x8 pa[2], vf[4];
#pragma unroll
      for (int mi = 0; mi < 2; ++mi)
        pa[mi] = *(const bf16x8*)&Pw[(mi * 16 + lo) * 64 + ks * 32 + hi * 8];
#pragma unroll
      for (int nj = 0; nj < 4; ++nj)
        vf[nj] = *(const bf16x8*)&Vs[(nj * 16 + lo) * 64 + ks * 32 + hi * 8];
#pragma unroll
      for (int mi = 0; mi < 2; ++mi)
#pragma unroll
        for (int nj = 0; nj < 4; ++nj)
          oacc[mi][nj] = __builtin_amdgcn_mfma_f32_16x16x32_bf16(pa[mi], vf[nj], oacc[mi][nj], 0, 0, 0);
    }
    __syncthreads();
  }

  // epilogue: ob[b][s][h*64+e] bf16
#pragma unroll
  for (int mi = 0; mi < 2; ++mi) {
#pragma unroll
    for (int r = 0; r < 4; ++r) {
      const int s = qrow0 + mi * 16 + hi * 4 + r;
      const float il = 1.0f / lrun[mi][r];
      const size_t base = ((size_t)bb2 * Ss + s) * Dd + hd * HD;
#pragma unroll
      for (int nj = 0; nj < 4; ++nj)
        ob[base + nj * 16 + lo] = f2bf(oacc[mi][nj][r] * il);
    }
  }
}

// ---------------------------------------------------------------------------
extern "C" void kernel_launch(void* const* d_in, const int* in_sizes, int n_in,
                              void* d_out, int out_size, void* d_ws, size_t ws_size,
                              hipStream_t stream)
{
  const float* x  = (const float*)d_in[0];
  const float* Wq = (const float*)d_in[1];
  const float* Wk = (const float*)d_in[2];
  const float* Wv = (const float*)d_in[3];
  const float* Wo = (const float*)d_in[4];
  const float* bo = (const float*)d_in[5];
  float* out = (float*)d_out;

  char* ws = (char*)d_ws;
  unsigned short* xb    = (unsigned short*)(ws);              //  8,388,608 B
  unsigned short* wqkvT = (unsigned short*)(ws + 8388608);    //  6,291,456 B
  unsigned short* woT   = (unsigned short*)(ws + 14680064);   //  2,097,152 B
  unsigned short* qb    = (unsigned short*)(ws + 16777216);   //  8,388,608 B
  unsigned short* kb    = (unsigned short*)(ws + 25165824);   //  8,388,608 B
  unsigned short* vtb   = (unsigned short*)(ws + 33554432);   //  8,388,608 B
  unsigned short* ob    = (unsigned short*)(ws + 41943040);   //  8,388,608 B (end 48 MiB)

  pack_x_k<<<4096, 256, 0, stream>>>((const float4*)x, xb, 1048576);
  tconv_k<<<dim3(1, 16, 16), 256, 0, stream>>>(Wq, wqkvT,           1024, 64);
  tconv_k<<<dim3(1, 16, 16), 256, 0, stream>>>(Wk, wqkvT + 1048576, 1024, 64);
  tconv_k<<<dim3(1, 16, 16), 256, 0, stream>>>(Wv, wqkvT + 2097152, 1024, 64);
  tconv_k<<<dim3(16, 16, 1), 256, 0, stream>>>(Wo, woT,             1024, 1024);

  // QKV: [4096x1024] @ [1024x3072]
  gemm_bt<0><<<dim3(24, 32), 256, 0, stream>>>(xb, wqkvT, 1024, 3072,
                                               qb, kb, vtb, nullptr, nullptr);
  // attention
  attn_fwd<<<dim3(16, 32), 256, 0, stream>>>(qb, kb, vtb, ob);
  // out-proj: [4096x1024] @ [1024x1024] + bo
  gemm_bt<1><<<dim3(8, 32), 256, 0, stream>>>(ob, woT, 1024, 1024,
                                              nullptr, nullptr, nullptr, out, bo);
}

// Round 2
// 194.621 us; speedup vs baseline: 1.1881x; 1.1881x over previous
//
#include <hip/hip_runtime.h>
#include <hip/hip_bf16.h>
#include <cstdint>

#define Hh 16
#define Dd 1024
#define HD 64
#define Bb 2
#define Ss 2048

typedef float f32x4 __attribute__((ext_vector_type(4)));
typedef __bf16 bf16x8 __attribute__((ext_vector_type(8)));

__device__ __forceinline__ unsigned short f2bf(float f) {
  union { float f; unsigned u; } v; v.f = f;
  unsigned r = (v.u + 0x7FFFu + ((v.u >> 16) & 1u)) >> 16;  // RNE, finite inputs
  return (unsigned short)r;
}

__device__ __forceinline__ void gld16(const void* g, void* l) {
  __builtin_amdgcn_global_load_lds(
      (__attribute__((address_space(1))) void*)(g),
      (__attribute__((address_space(3))) void*)(l),
      16, 0, 0);
}

// ---------------------------------------------------------------------------
// Pack x (fp32 -> bf16), vectorized float4 -> ushort4
// ---------------------------------------------------------------------------
__global__ __launch_bounds__(256)
void pack_x_k(const float4* __restrict__ x, unsigned short* __restrict__ xb, int n4) {
  const int i = blockIdx.x * blockDim.x + threadIdx.x;
  if (i >= n4) return;
  const float4 v = x[i];
  ushort4 o;
  o.x = f2bf(v.x); o.y = f2bf(v.y); o.z = f2bf(v.z); o.w = f2bf(v.w);
  *(ushort4*)&xb[(size_t)i * 4] = o;
}

// ---------------------------------------------------------------------------
// Batched transpose + scale + fp32->bf16: out[m][c][r] = in[m][r][c] * scale
// grid: (C/64, R/64, nmat), block 256
// ---------------------------------------------------------------------------
__global__ __launch_bounds__(256)
void tconv_k(const float* __restrict__ in, unsigned short* __restrict__ out,
             int R, int C, float scale) {
  __shared__ float T[64][65];
  const int m = blockIdx.z;
  const float* src = in + (size_t)m * R * C;
  unsigned short* dst = out + (size_t)m * R * C;
  const int c0 = blockIdx.x * 64, r0 = blockIdx.y * 64;
  const int tx = threadIdx.x & 63, ty = threadIdx.x >> 6;
#pragma unroll
  for (int it = 0; it < 16; ++it) {
    const int i = ty + it * 4;
    T[i][tx] = src[(size_t)(r0 + i) * C + c0 + tx];
  }
  __syncthreads();
#pragma unroll
  for (int it = 0; it < 16; ++it) {
    const int jj = ty + it * 4;
    dst[(size_t)(c0 + jj) * R + r0 + tx] = f2bf(T[tx][jj] * scale);
  }
}

// ---------------------------------------------------------------------------
// m97-style bf16 GEMM: A[M][K] row-major, Bt[N][K] row-major (= B^T).
// 128x128 tile, BK=64, 4 waves, 16x16x32 MFMA, global_load_lds width 16.
// EPI 0: QKV scatter (q,k as [bh][s][e] bf16; v transposed [bh][e][s] bf16)
// EPI 1: fp32 out + bias
// ---------------------------------------------------------------------------
template <int EPI>
__global__ __launch_bounds__(256)
void gemm_bt(const unsigned short* __restrict__ A,
             const unsigned short* __restrict__ Bt,
             int K, int Ndim,
             unsigned short* __restrict__ q_out,
             unsigned short* __restrict__ k_out,
             unsigned short* __restrict__ vt_out,
             float* __restrict__ o_out,
             const float* __restrict__ bias)
{
  __shared__ unsigned short As[128 * 64];
  __shared__ unsigned short Bs[128 * 64];

  const int tid = threadIdx.x;
  const int w = tid >> 6, lane = tid & 63;
  const int lo = lane & 15, hi = lane >> 4;
  const int wr = w >> 1, wc = w & 1;
  const int row0 = blockIdx.y * 128;
  const int col0 = blockIdx.x * 128;

  f32x4 acc[4][4] = {};

  const int er = w * 32 + (lane >> 3);   // staging row for c=0
  const int ec = (lane & 7) * 8;         // staging col (elements)

  for (int k0 = 0; k0 < K; k0 += 64) {
#pragma unroll
    for (int c = 0; c < 4; ++c) {
      const int rr = er + c * 8;
      gld16(A  + (size_t)(row0 + rr) * K + (k0 + ec), (char*)As + (size_t)(w * 4 + c) * 1024);
      gld16(Bt + (size_t)(col0 + rr) * K + (k0 + ec), (char*)Bs + (size_t)(w * 4 + c) * 1024);
    }
    __syncthreads();
#pragma unroll
    for (int ks = 0; ks < 2; ++ks) {
      bf16x8 af[4], bfr[4];
#pragma unroll
      for (int i = 0; i < 4; ++i)
        af[i] = *(const bf16x8*)&As[(wr * 64 + i * 16 + lo) * 64 + ks * 32 + hi * 8];
#pragma unroll
      for (int j = 0; j < 4; ++j)
        bfr[j] = *(const bf16x8*)&Bs[(wc * 64 + j * 16 + lo) * 64 + ks * 32 + hi * 8];
#pragma unroll
      for (int i = 0; i < 4; ++i)
#pragma unroll
        for (int j = 0; j < 4; ++j)
          acc[i][j] = __builtin_amdgcn_mfma_f32_16x16x32_bf16(af[i], bfr[j], acc[i][j], 0, 0, 0);
    }
    __syncthreads();
  }

#pragma unroll
  for (int i = 0; i < 4; ++i) {
    const int grow = row0 + wr * 64 + i * 16 + hi * 4;  // + r
#pragma unroll
    for (int j = 0; j < 4; ++j) {
      const int gcol = col0 + wc * 64 + j * 16 + lo;
      if (EPI == 0) {
        const int p  = gcol >> 10;
        const int hd = (gcol >> 6) & 15;
        const int e  = gcol & 63;
        const int bb2 = grow >> 11;
        const int s   = grow & 2047;
        const int bh  = bb2 * Hh + hd;
        if (p == 2) {
          const size_t base = ((size_t)bh * HD + e) * Ss + s;  // V^T: s contiguous over r
          ushort4 pk;
          pk.x = f2bf(acc[i][j][0]); pk.y = f2bf(acc[i][j][1]);
          pk.z = f2bf(acc[i][j][2]); pk.w = f2bf(acc[i][j][3]);
          *(ushort4*)&vt_out[base] = pk;
        } else {
          unsigned short* dst = (p == 0) ? q_out : k_out;
          const size_t base = ((size_t)bh * Ss + s) * HD + e;
#pragma unroll
          for (int r = 0; r < 4; ++r) dst[base + (size_t)r * HD] = f2bf(acc[i][j][r]);
        }
      } else {
        const size_t base = (size_t)grow * Ndim + gcol;
        const float bv = bias[gcol];
#pragma unroll
        for (int r = 0; r < 4; ++r) o_out[base + (size_t)r * Ndim] = acc[i][j][r] + bv;
      }
    }
  }
}

// ---------------------------------------------------------------------------
// Flash attention, causal. grid (B*H, S/64), 128 thr (2 waves x 32 q-rows).
// Q in registers (Wq pre-scaled by 1/8); K tile [64 kk][64 e] and V^T tile
// [64 e][64 kk] XOR-swizzled in LDS (linear gld_lds dest + pre-swizzled
// global source column); double-buffered, stage(t+1) issued before compute(t),
// one barrier per tile. Online softmax wave-parallel over the 16-lane group;
// P via per-wave swizzled LDS. Causal mask only on the diagonal tile.
// ---------------------------------------------------------------------------
__global__ __launch_bounds__(128)
void attn_fwd(const unsigned short* __restrict__ qb,
              const unsigned short* __restrict__ kb,
              const unsigned short* __restrict__ vtb,
              unsigned short* __restrict__ ob)
{
  __shared__ unsigned short Ks[2][64 * 64];
  __shared__ unsigned short Vs[2][64 * 64];
  __shared__ unsigned short Ps[2][32 * 64];

  const int qt = 31 - blockIdx.y;        // reversed: heaviest blocks first
  const int bh = blockIdx.x;
  const int bb2 = bh >> 4;
  const int hd = bh & 15;

  const unsigned short* Q  = qb  + (size_t)bh * Ss * HD;
  const unsigned short* Kg = kb  + (size_t)bh * Ss * HD;
  const unsigned short* Vt = vtb + (size_t)bh * HD * Ss;

  const int tid = threadIdx.x;
  const int w = tid >> 6, lane = tid & 63;
  const int lo = lane & 15, hi = lane >> 4;
  const int qrow0 = qt * 64 + w * 32;

  // staging geometry: LDS linear dest, pre-swizzled global source column
  const int srow = w * 8 + (lane >> 3);                 // + c*16
  const int scol = ((lane & 7) ^ (lane >> 3)) * 8;      // swizzled col (elems)

#define STAGE(bi, kv)                                                     \
  _Pragma("unroll")                                                       \
  for (int c = 0; c < 4; ++c) {                                           \
    const int rr = c * 16 + srow;                                         \
    gld16(Kg + (size_t)((kv) + rr) * HD + scol,                           \
          (char*)&Ks[bi][0] + c * 2048 + w * 1024);                       \
    gld16(Vt + (size_t)rr * Ss + (kv) + scol,                             \
          (char*)&Vs[bi][0] + c * 2048 + w * 1024);                       \
  }

  bf16x8 qf[2][2];
#pragma unroll
  for (int mi = 0; mi < 2; ++mi)
#pragma unroll
    for (int ks = 0; ks < 2; ++ks)
      qf[mi][ks] = *(const bf16x8*)&Q[(size_t)(qrow0 + mi * 16 + lo) * HD + ks * 32 + hi * 8];

  f32x4 oacc[2][4] = {};
  float mrun[2][4], lrun[2][4];
#pragma unroll
  for (int mi = 0; mi < 2; ++mi)
#pragma unroll
    for (int r = 0; r < 4; ++r) { mrun[mi][r] = -INFINITY; lrun[mi][r] = 0.f; }

  const int ntiles = qt + 1;   // causal: kk-tiles 0..qt
  const int swl = (lo & 7) << 4;  // read-side XOR for rows where row&7 == lo&7

  STAGE(0, 0);
  __syncthreads();

  int cur = 0;
  for (int t = 0; t < ntiles; ++t) {
    if (t + 1 < ntiles) { STAGE(cur ^ 1, (t + 1) * 64); }

    const int kv0 = t * 64;
    const bool diag = (t == qt);

    // S = Q K^T  (score scale folded into Wq)
    f32x4 sacc[2][4] = {};
#pragma unroll
    for (int ks = 0; ks < 2; ++ks) {
      bf16x8 kf[4];
#pragma unroll
      for (int nj = 0; nj < 4; ++nj)
        kf[nj] = *(const bf16x8*)((const char*)&Ks[cur][0] +
                 (nj * 16 + lo) * 128 + ((ks * 64 + hi * 16) ^ swl));
#pragma unroll
      for (int mi = 0; mi < 2; ++mi)
#pragma unroll
        for (int nj = 0; nj < 4; ++nj)
          sacc[mi][nj] = __builtin_amdgcn_mfma_f32_16x16x32_bf16(qf[mi][ks], kf[nj], sacc[mi][nj], 0, 0, 0);
    }

    // online softmax (row stats across the 16-lane group)
    float pp[2][4][4];
#pragma unroll
    for (int mi = 0; mi < 2; ++mi) {
#pragma unroll
      for (int r = 0; r < 4; ++r) {
        const int q = qrow0 + mi * 16 + hi * 4 + r;
        float sv[4];
        float rowmax = -INFINITY;
#pragma unroll
        for (int nj = 0; nj < 4; ++nj) {
          float s = sacc[mi][nj][r];
          if (diag) { const int kk = kv0 + nj * 16 + lo; s = (kk <= q) ? s : -INFINITY; }
          sv[nj] = s;
          rowmax = fmaxf(rowmax, s);
        }
#pragma unroll
        for (int d = 1; d < 16; d <<= 1)
          rowmax = fmaxf(rowmax, __shfl_xor(rowmax, d, 64));
        const float mnew = fmaxf(mrun[mi][r], rowmax);
        float rsum = 0.f;
#pragma unroll
        for (int nj = 0; nj < 4; ++nj) {
          const float p = __expf(sv[nj] - mnew);
          pp[mi][nj][r] = p;
          rsum += p;
        }
#pragma unroll
        for (int d = 1; d < 16; d <<= 1)
          rsum += __shfl_xor(rsum, d, 64);
        const float resc = __expf(mrun[mi][r] - mnew);
        lrun[mi][r] = lrun[mi][r] * resc + rsum;
        mrun[mi][r] = mnew;
#pragma unroll
        for (int nj = 0; nj < 4; ++nj)
          oacc[mi][nj][r] *= resc;
      }
    }

    // P -> per-wave swizzled LDS (reshape D-layout -> A-fragment layout)
    unsigned short* Pw = &Ps[w][0];
#pragma unroll
    for (int mi = 0; mi < 2; ++mi)
#pragma unroll
      for (int nj = 0; nj < 4; ++nj)
#pragma unroll
        for (int r = 0; r < 4; ++r) {
          const int prow = mi * 16 + hi * 4 + r;
          const int pcb = (nj * 32 + lo * 2) ^ ((prow & 7) << 4);
          *(unsigned short*)((char*)Pw + prow * 128 + pcb) = f2bf(pp[mi][nj][r]);
        }

    // O += P V
#pragma unroll
    for (int ks = 0; ks < 2; ++ks) {
      bf16x8 pa[2], vf[4];
#pragma unroll
      for (int mi = 0; mi < 2; ++mi)
        pa[mi] = *(const bf16x8*)((const char*)Pw +
                 (mi * 16 + lo) * 128 + ((ks * 64 + hi * 16) ^ swl));
#pragma unroll
      for (int nj = 0; nj < 4; ++nj)
        vf[nj] = *(const bf16x8*)((const char*)&Vs[cur][0] +
                 (nj * 16 + lo) * 128 + ((ks * 64 + hi * 16) ^ swl));
#pragma unroll
      for (int mi = 0; mi < 2; ++mi)
#pragma unroll
        for (int nj = 0; nj < 4; ++nj)
          oacc[mi][nj] = __builtin_amdgcn_mfma_f32_16x16x32_bf16(pa[mi], vf[nj], oacc[mi][nj], 0, 0, 0);
    }

    __syncthreads();
    cur ^= 1;
  }
#undef STAGE

  // epilogue: ob[b][s][h*64+e] bf16
#pragma unroll
  for (int mi = 0; mi < 2; ++mi) {
#pragma unroll
    for (int r = 0; r < 4; ++r) {
      const int s = qrow0 + mi * 16 + hi * 4 + r;
      const float il = 1.0f / lrun[mi][r];
      const size_t base = ((size_t)bb2 * Ss + s) * Dd + hd * HD;
#pragma unroll
      for (int nj = 0; nj < 4; ++nj)
        ob[base + nj * 16 + lo] = f2bf(oacc[mi][nj][r] * il);
    }
  }
}

// ---------------------------------------------------------------------------
extern "C" void kernel_launch(void* const* d_in, const int* in_sizes, int n_in,
                              void* d_out, int out_size, void* d_ws, size_t ws_size,
                              hipStream_t stream)
{
  const float* x  = (const float*)d_in[0];
  const float* Wq = (const float*)d_in[1];
  const float* Wk = (const float*)d_in[2];
  const float* Wv = (const float*)d_in[3];
  const float* Wo = (const float*)d_in[4];
  const float* bo = (const float*)d_in[5];
  float* out = (float*)d_out;

  char* ws = (char*)d_ws;
  unsigned short* xb    = (unsigned short*)(ws);              //  8,388,608 B
  unsigned short* wqkvT = (unsigned short*)(ws + 8388608);    //  6,291,456 B
  unsigned short* woT   = (unsigned short*)(ws + 14680064);   //  2,097,152 B
  unsigned short* qb    = (unsigned short*)(ws + 16777216);   //  8,388,608 B
  unsigned short* kb    = (unsigned short*)(ws + 25165824);   //  8,388,608 B
  unsigned short* vtb   = (unsigned short*)(ws + 33554432);   //  8,388,608 B
  unsigned short* ob    = (unsigned short*)(ws + 41943040);   //  8,388,608 B (end 48 MiB)

  pack_x_k<<<4096, 256, 0, stream>>>((const float4*)x, xb, 1048576);
  // Wq carries the 1/sqrt(HD)=1/8 score scale (exact in bf16: power of two)
  tconv_k<<<dim3(1, 16, 16), 256, 0, stream>>>(Wq, wqkvT,           1024, 64, 0.125f);
  tconv_k<<<dim3(1, 16, 16), 256, 0, stream>>>(Wk, wqkvT + 1048576, 1024, 64, 1.0f);
  tconv_k<<<dim3(1, 16, 16), 256, 0, stream>>>(Wv, wqkvT + 2097152, 1024, 64, 1.0f);
  tconv_k<<<dim3(16, 16, 1), 256, 0, stream>>>(Wo, woT,             1024, 1024, 1.0f);

  // QKV: [4096x1024] @ [1024x3072]
  gemm_bt<0><<<dim3(24, 32), 256, 0, stream>>>(xb, wqkvT, 1024, 3072,
                                               qb, kb, vtb, nullptr, nullptr);
  // attention
  attn_fwd<<<dim3(32, 32), 128, 0, stream>>>(qb, kb, vtb, ob);
  // out-proj: [4096x1024] @ [1024x1024] + bo
  gemm_bt<1><<<dim3(8, 32), 256, 0, stream>>>(ob, woT, 1024, 1024,
                                              nullptr, nullptr, nullptr, out, bo);
}

// Round 3
// 173.444 us; speedup vs baseline: 1.3332x; 1.1221x over previous
//
#include <hip/hip_runtime.h>
#include <hip/hip_bf16.h>
#include <cstdint>

#define Hh 16
#define Dd 1024
#define HD 64
#define Bb 2
#define Ss 2048

typedef float f32x4 __attribute__((ext_vector_type(4)));
typedef __bf16 bf16x8 __attribute__((ext_vector_type(8)));

__device__ __forceinline__ unsigned short f2bf(float f) {
  union { float f; unsigned u; } v; v.f = f;
  unsigned r = (v.u + 0x7FFFu + ((v.u >> 16) & 1u)) >> 16;  // RNE, finite inputs
  return (unsigned short)r;
}

__device__ __forceinline__ void gld16(const void* g, void* l) {
  __builtin_amdgcn_global_load_lds(
      (__attribute__((address_space(1))) void*)(g),
      (__attribute__((address_space(3))) void*)(l),
      16, 0, 0);
}

// ---------------------------------------------------------------------------
// Pack x (fp32 -> bf16), vectorized float4 -> ushort4
// ---------------------------------------------------------------------------
__global__ __launch_bounds__(256)
void pack_x_k(const float4* __restrict__ x, unsigned short* __restrict__ xb, int n4) {
  const int i = blockIdx.x * blockDim.x + threadIdx.x;
  if (i >= n4) return;
  const float4 v = x[i];
  ushort4 o;
  o.x = f2bf(v.x); o.y = f2bf(v.y); o.z = f2bf(v.z); o.w = f2bf(v.w);
  *(ushort4*)&xb[(size_t)i * 4] = o;
}

// ---------------------------------------------------------------------------
// Batched transpose + scale + fp32->bf16: out[m][c][r] = in[m][r][c] * scale
// grid: (C/64, R/64, nmat), block 256
// ---------------------------------------------------------------------------
__global__ __launch_bounds__(256)
void tconv_k(const float* __restrict__ in, unsigned short* __restrict__ out,
             int R, int C, float scale) {
  __shared__ float T[64][65];
  const int m = blockIdx.z;
  const float* src = in + (size_t)m * R * C;
  unsigned short* dst = out + (size_t)m * R * C;
  const int c0 = blockIdx.x * 64, r0 = blockIdx.y * 64;
  const int tx = threadIdx.x & 63, ty = threadIdx.x >> 6;
#pragma unroll
  for (int it = 0; it < 16; ++it) {
    const int i = ty + it * 4;
    T[i][tx] = src[(size_t)(r0 + i) * C + c0 + tx];
  }
  __syncthreads();
#pragma unroll
  for (int it = 0; it < 16; ++it) {
    const int jj = ty + it * 4;
    dst[(size_t)(c0 + jj) * R + r0 + tx] = f2bf(T[tx][jj] * scale);
  }
}

// ---------------------------------------------------------------------------
// m97-style bf16 GEMM: A[M][K] row-major, Bt[N][K] row-major (= B^T).
// 128x128 tile, BK=64, 4 waves, 16x16x32 MFMA, global_load_lds width 16.
// EPI 0: QKV scatter (q,k as [bh][s][e] bf16; v transposed [bh][e][s] bf16)
// EPI 1: fp32 out + bias
// ---------------------------------------------------------------------------
template <int EPI>
__global__ __launch_bounds__(256)
void gemm_bt(const unsigned short* __restrict__ A,
             const unsigned short* __restrict__ Bt,
             int K, int Ndim,
             unsigned short* __restrict__ q_out,
             unsigned short* __restrict__ k_out,
             unsigned short* __restrict__ vt_out,
             float* __restrict__ o_out,
             const float* __restrict__ bias)
{
  __shared__ unsigned short As[128 * 64];
  __shared__ unsigned short Bs[128 * 64];

  const int tid = threadIdx.x;
  const int w = tid >> 6, lane = tid & 63;
  const int lo = lane & 15, hi = lane >> 4;
  const int wr = w >> 1, wc = w & 1;
  const int row0 = blockIdx.y * 128;
  const int col0 = blockIdx.x * 128;

  f32x4 acc[4][4] = {};

  const int er = w * 32 + (lane >> 3);   // staging row for c=0
  const int ec = (lane & 7) * 8;         // staging col (elements)

  for (int k0 = 0; k0 < K; k0 += 64) {
#pragma unroll
    for (int c = 0; c < 4; ++c) {
      const int rr = er + c * 8;
      gld16(A  + (size_t)(row0 + rr) * K + (k0 + ec), (char*)As + (size_t)(w * 4 + c) * 1024);
      gld16(Bt + (size_t)(col0 + rr) * K + (k0 + ec), (char*)Bs + (size_t)(w * 4 + c) * 1024);
    }
    __syncthreads();
#pragma unroll
    for (int ks = 0; ks < 2; ++ks) {
      bf16x8 af[4], bfr[4];
#pragma unroll
      for (int i = 0; i < 4; ++i)
        af[i] = *(const bf16x8*)&As[(wr * 64 + i * 16 + lo) * 64 + ks * 32 + hi * 8];
#pragma unroll
      for (int j = 0; j < 4; ++j)
        bfr[j] = *(const bf16x8*)&Bs[(wc * 64 + j * 16 + lo) * 64 + ks * 32 + hi * 8];
#pragma unroll
      for (int i = 0; i < 4; ++i)
#pragma unroll
        for (int j = 0; j < 4; ++j)
          acc[i][j] = __builtin_amdgcn_mfma_f32_16x16x32_bf16(af[i], bfr[j], acc[i][j], 0, 0, 0);
    }
    __syncthreads();
  }

#pragma unroll
  for (int i = 0; i < 4; ++i) {
    const int grow = row0 + wr * 64 + i * 16 + hi * 4;  // + r
#pragma unroll
    for (int j = 0; j < 4; ++j) {
      const int gcol = col0 + wc * 64 + j * 16 + lo;
      if (EPI == 0) {
        const int p  = gcol >> 10;
        const int hd = (gcol >> 6) & 15;
        const int e  = gcol & 63;
        const int bb2 = grow >> 11;
        const int s   = grow & 2047;
        const int bh  = bb2 * Hh + hd;
        if (p == 2) {
          const size_t base = ((size_t)bh * HD + e) * Ss + s;  // V^T: s contiguous over r
          ushort4 pk;
          pk.x = f2bf(acc[i][j][0]); pk.y = f2bf(acc[i][j][1]);
          pk.z = f2bf(acc[i][j][2]); pk.w = f2bf(acc[i][j][3]);
          *(ushort4*)&vt_out[base] = pk;
        } else {
          unsigned short* dst = (p == 0) ? q_out : k_out;
          const size_t base = ((size_t)bh * Ss + s) * HD + e;
#pragma unroll
          for (int r = 0; r < 4; ++r) dst[base + (size_t)r * HD] = f2bf(acc[i][j][r]);
        }
      } else {
        const size_t base = (size_t)grow * Ndim + gcol;
        const float bv = bias[gcol];
#pragma unroll
        for (int r = 0; r < 4; ++r) o_out[base + (size_t)r * Ndim] = acc[i][j][r] + bv;
      }
    }
  }
}

// ---------------------------------------------------------------------------
// Flash attention, causal, counter-diagonal paired.
// grid (B*H, 16 pairs), 128 thr (2 waves x 32 q-rows). Block processes q-tile
// (31-pr) then q-tile (pr): 33 tile-steps for every block (uniform).
// Q in registers; Wq carries 0.125*log2(e) so scores are in log2 domain and
// all exponentials are single v_exp_f32. K/V^T tiles XOR-swizzled in LDS,
// double-buffered, next tile (incl. next phase's tile 0) prefetched before
// compute. Row max via 4-step shfl; row SUM via MFMA-with-ones on the P
// fragments (deletes the sum shfl chain). Defer-max (THR=8, log2) skips the
// rescale pass on most tiles. P via per-wave swizzled LDS (wave-local, no
// barrier needed).
// ---------------------------------------------------------------------------
__global__ __launch_bounds__(128)
void attn_fwd(const unsigned short* __restrict__ qb,
              const unsigned short* __restrict__ kb,
              const unsigned short* __restrict__ vtb,
              unsigned short* __restrict__ ob)
{
  __shared__ unsigned short Ks[2][64 * 64];
  __shared__ unsigned short Vs[2][64 * 64];
  __shared__ unsigned short Ps[2][32 * 64];

  const int pr = blockIdx.y;             // pair index 0..15
  const int bh = blockIdx.x;
  const int bb2 = bh >> 4;
  const int hd = bh & 15;

  const unsigned short* Q  = qb  + (size_t)bh * Ss * HD;
  const unsigned short* Kg = kb  + (size_t)bh * Ss * HD;
  const unsigned short* Vt = vtb + (size_t)bh * HD * Ss;

  const int tid = threadIdx.x;
  const int w = tid >> 6, lane = tid & 63;
  const int lo = lane & 15, hi = lane >> 4;

  // staging geometry: LDS linear dest, pre-swizzled global source column
  const int srow = w * 8 + (lane >> 3);                 // + c*16
  const int scol = ((lane & 7) ^ (lane >> 3)) * 8;      // swizzled col (elems)

#define STAGE(bi, kv)                                                     \
  _Pragma("unroll")                                                       \
  for (int c = 0; c < 4; ++c) {                                           \
    const int rr = c * 16 + srow;                                         \
    gld16(Kg + (size_t)((kv) + rr) * HD + scol,                           \
          (char*)&Ks[bi][0] + c * 2048 + w * 1024);                       \
    gld16(Vt + (size_t)rr * Ss + (kv) + scol,                             \
          (char*)&Vs[bi][0] + c * 2048 + w * 1024);                       \
  }

  const int swl = (lo & 7) << 4;   // read-side XOR (row&7 == lo&7 for our rows)

  bf16x8 vones;
#pragma unroll
  for (int j = 0; j < 8; ++j) vones[j] = (__bf16)1.0f;

  STAGE(0, 0);
  __syncthreads();

  int cur = 0;
#pragma unroll
  for (int ph = 0; ph < 2; ++ph) {
    const int qt = (ph == 0) ? (31 - pr) : pr;
    const int qrow0 = qt * 64 + w * 32;
    const int ntiles = qt + 1;

    bf16x8 qf[2][2];
#pragma unroll
    for (int mi = 0; mi < 2; ++mi)
#pragma unroll
      for (int ks = 0; ks < 2; ++ks)
        qf[mi][ks] = *(const bf16x8*)&Q[(size_t)(qrow0 + mi * 16 + lo) * HD + ks * 32 + hi * 8];

    f32x4 oacc[2][4] = {};
    float m2[2][4], l2[2][4];
#pragma unroll
    for (int mi = 0; mi < 2; ++mi)
#pragma unroll
      for (int r = 0; r < 4; ++r) { m2[mi][r] = -INFINITY; l2[mi][r] = 0.f; }

    for (int t = 0; t < ntiles; ++t) {
      if (t + 1 < ntiles)      { STAGE(cur ^ 1, (t + 1) * 64); }
      else if (ph == 0)        { STAGE(cur ^ 1, 0); }   // next phase's tile 0

      const int kv0 = t * 64;
      const bool diag = (t == qt);

      // S = Q K^T  (log2-domain scores; scale folded into Wq)
      f32x4 sacc[2][4] = {};
#pragma unroll
      for (int ks = 0; ks < 2; ++ks) {
        bf16x8 kf[4];
#pragma unroll
        for (int nj = 0; nj < 4; ++nj)
          kf[nj] = *(const bf16x8*)((const char*)&Ks[cur][0] +
                   (nj * 16 + lo) * 128 + ((ks * 64 + hi * 16) ^ swl));
#pragma unroll
        for (int mi = 0; mi < 2; ++mi)
#pragma unroll
          for (int nj = 0; nj < 4; ++nj)
            sacc[mi][nj] = __builtin_amdgcn_mfma_f32_16x16x32_bf16(qf[mi][ks], kf[nj], sacc[mi][nj], 0, 0, 0);
      }

      // mask (diag tile only) + per-row max over the 16-lane group
      float rmx[2][4];
#pragma unroll
      for (int mi = 0; mi < 2; ++mi) {
#pragma unroll
        for (int r = 0; r < 4; ++r) {
          if (diag) {
            const int q = qrow0 + mi * 16 + hi * 4 + r;
#pragma unroll
            for (int nj = 0; nj < 4; ++nj) {
              const int kk = kv0 + nj * 16 + lo;
              if (kk > q) sacc[mi][nj][r] = -INFINITY;
            }
          }
          float rm = fmaxf(fmaxf(sacc[mi][0][r], sacc[mi][1][r]),
                           fmaxf(sacc[mi][2][r], sacc[mi][3][r]));
#pragma unroll
          for (int d = 1; d < 16; d <<= 1)
            rm = fmaxf(rm, __shfl_xor(rm, d, 64));
          rmx[mi][r] = rm;
        }
      }

      // defer-max: rescale only when some row's max grew past THR=8 (log2)
      float dmax = -INFINITY;
#pragma unroll
      for (int mi = 0; mi < 2; ++mi)
#pragma unroll
        for (int r = 0; r < 4; ++r)
          dmax = fmaxf(dmax, rmx[mi][r] - m2[mi][r]);
      if (!__all(dmax <= 8.0f)) {
#pragma unroll
        for (int mi = 0; mi < 2; ++mi)
#pragma unroll
          for (int r = 0; r < 4; ++r) {
            const float mn = fmaxf(m2[mi][r], rmx[mi][r]);
            const float rc = __builtin_amdgcn_exp2f(m2[mi][r] - mn);
            m2[mi][r] = mn;
            l2[mi][r] *= rc;
#pragma unroll
            for (int nj = 0; nj < 4; ++nj)
              oacc[mi][nj][r] *= rc;
          }
      }

      // P = exp2(S - m) -> per-wave swizzled LDS (wave-local, no barrier)
      unsigned short* Pw = &Ps[w][0];
#pragma unroll
      for (int mi = 0; mi < 2; ++mi)
#pragma unroll
        for (int nj = 0; nj < 4; ++nj)
#pragma unroll
          for (int r = 0; r < 4; ++r) {
            const float p = __builtin_amdgcn_exp2f(sacc[mi][nj][r] - m2[mi][r]);
            const int prow = mi * 16 + hi * 4 + r;
            const int pcb = (nj * 32 + lo * 2) ^ ((prow & 7) << 4);
            *(__bf16*)((char*)Pw + prow * 128 + pcb) = (__bf16)p;
          }

      // O += P V ; row-sums via MFMA-with-ones on the same P fragments
      f32x4 osum[2] = {};
#pragma unroll
      for (int ks = 0; ks < 2; ++ks) {
        bf16x8 pa[2], vf[4];
#pragma unroll
        for (int mi = 0; mi < 2; ++mi)
          pa[mi] = *(const bf16x8*)((const char*)Pw +
                   (mi * 16 + lo) * 128 + ((ks * 64 + hi * 16) ^ swl));
#pragma unroll
        for (int nj = 0; nj < 4; ++nj)
          vf[nj] = *(const bf16x8*)((const char*)&Vs[cur][0] +
                   (nj * 16 + lo) * 128 + ((ks * 64 + hi * 16) ^ swl));
#pragma unroll
        for (int mi = 0; mi < 2; ++mi)
#pragma unroll
          for (int nj = 0; nj < 4; ++nj)
            oacc[mi][nj] = __builtin_amdgcn_mfma_f32_16x16x32_bf16(pa[mi], vf[nj], oacc[mi][nj], 0, 0, 0);
#pragma unroll
        for (int mi = 0; mi < 2; ++mi)
          osum[mi] = __builtin_amdgcn_mfma_f32_16x16x32_bf16(pa[mi], vones, osum[mi], 0, 0, 0);
      }
#pragma unroll
      for (int mi = 0; mi < 2; ++mi)
#pragma unroll
        for (int r = 0; r < 4; ++r)
          l2[mi][r] += osum[mi][r];

      __syncthreads();
      cur ^= 1;
    }

    // epilogue: ob[b][s][h*64+e] bf16
#pragma unroll
    for (int mi = 0; mi < 2; ++mi) {
#pragma unroll
      for (int r = 0; r < 4; ++r) {
        const int s = qrow0 + mi * 16 + hi * 4 + r;
        const float il = 1.0f / l2[mi][r];
        const size_t base = ((size_t)bb2 * Ss + s) * Dd + hd * HD;
#pragma unroll
        for (int nj = 0; nj < 4; ++nj)
          ob[base + nj * 16 + lo] = f2bf(oacc[mi][nj][r] * il);
      }
    }
  }
#undef STAGE
}

// ---------------------------------------------------------------------------
extern "C" void kernel_launch(void* const* d_in, const int* in_sizes, int n_in,
                              void* d_out, int out_size, void* d_ws, size_t ws_size,
                              hipStream_t stream)
{
  const float* x  = (const float*)d_in[0];
  const float* Wq = (const float*)d_in[1];
  const float* Wk = (const float*)d_in[2];
  const float* Wv = (const float*)d_in[3];
  const float* Wo = (const float*)d_in[4];
  const float* bo = (const float*)d_in[5];
  float* out = (float*)d_out;

  char* ws = (char*)d_ws;
  unsigned short* xb    = (unsigned short*)(ws);              //  8,388,608 B
  unsigned short* wqkvT = (unsigned short*)(ws + 8388608);    //  6,291,456 B
  unsigned short* woT   = (unsigned short*)(ws + 14680064);   //  2,097,152 B
  unsigned short* qb    = (unsigned short*)(ws + 16777216);   //  8,388,608 B
  unsigned short* kb    = (unsigned short*)(ws + 25165824);   //  8,388,608 B
  unsigned short* vtb   = (unsigned short*)(ws + 33554432);   //  8,388,608 B
  unsigned short* ob    = (unsigned short*)(ws + 41943040);   //  8,388,608 B (end 48 MiB)

  pack_x_k<<<4096, 256, 0, stream>>>((const float4*)x, xb, 1048576);
  // Wq carries 1/sqrt(HD) * log2(e) so attention scores land in log2 domain
  tconv_k<<<dim3(1, 16, 16), 256, 0, stream>>>(Wq, wqkvT,           1024, 64, 0.18033688011112042f);
  tconv_k<<<dim3(1, 16, 16), 256, 0, stream>>>(Wk, wqkvT + 1048576, 1024, 64, 1.0f);
  tconv_k<<<dim3(1, 16, 16), 256, 0, stream>>>(Wv, wqkvT + 2097152, 1024, 64, 1.0f);
  tconv_k<<<dim3(16, 16, 1), 256, 0, stream>>>(Wo, woT,             1024, 1024, 1.0f);

  // QKV: [4096x1024] @ [1024x3072]
  gemm_bt<0><<<dim3(24, 32), 256, 0, stream>>>(xb, wqkvT, 1024, 3072,
                                               qb, kb, vtb, nullptr, nullptr);
  // attention (counter-diagonal pairs: uniform 33 tile-steps/block)
  attn_fwd<<<dim3(32, 16), 128, 0, stream>>>(qb, kb, vtb, ob);
  // out-proj: [4096x1024] @ [1024x1024] + bo
  gemm_bt<1><<<dim3(8, 32), 256, 0, stream>>>(ob, woT, 1024, 1024,
                                              nullptr, nullptr, nullptr, out, bo);
}

// Round 4
// 140.338 us; speedup vs baseline: 1.6477x; 1.2359x over previous
//
#include <hip/hip_runtime.h>
#include <hip/hip_bf16.h>
#include <cstdint>

#define Hh 16
#define Dd 1024
#define HD 64
#define Bb 2
#define Ss 2048

typedef float f32x4 __attribute__((ext_vector_type(4)));
typedef __bf16 bf16x8 __attribute__((ext_vector_type(8)));

__device__ __forceinline__ unsigned short f2bf(float f) {
  union { float f; unsigned u; } v; v.f = f;
  unsigned r = (v.u + 0x7FFFu + ((v.u >> 16) & 1u)) >> 16;  // RNE, finite inputs
  return (unsigned short)r;
}

__device__ __forceinline__ void gld16(const void* g, void* l) {
  __builtin_amdgcn_global_load_lds(
      (__attribute__((address_space(1))) void*)(g),
      (__attribute__((address_space(3))) void*)(l),
      16, 0, 0);
}

// ---------------------------------------------------------------------------
// Pack x (fp32 -> bf16), vectorized float4 -> ushort4
// ---------------------------------------------------------------------------
__global__ __launch_bounds__(256)
void pack_x_k(const float4* __restrict__ x, unsigned short* __restrict__ xb, int n4) {
  const int i = blockIdx.x * blockDim.x + threadIdx.x;
  if (i >= n4) return;
  const float4 v = x[i];
  ushort4 o;
  o.x = f2bf(v.x); o.y = f2bf(v.y); o.z = f2bf(v.z); o.w = f2bf(v.w);
  *(ushort4*)&xb[(size_t)i * 4] = o;
}

// ---------------------------------------------------------------------------
// Batched transpose + scale + fp32->bf16: out[m][c][r] = in[m][r][c] * scale
// grid: (C/64, R/64, nmat), block 256
// ---------------------------------------------------------------------------
__global__ __launch_bounds__(256)
void tconv_k(const float* __restrict__ in, unsigned short* __restrict__ out,
             int R, int C, float scale) {
  __shared__ float T[64][65];
  const int m = blockIdx.z;
  const float* src = in + (size_t)m * R * C;
  unsigned short* dst = out + (size_t)m * R * C;
  const int c0 = blockIdx.x * 64, r0 = blockIdx.y * 64;
  const int tx = threadIdx.x & 63, ty = threadIdx.x >> 6;
#pragma unroll
  for (int it = 0; it < 16; ++it) {
    const int i = ty + it * 4;
    T[i][tx] = src[(size_t)(r0 + i) * C + c0 + tx];
  }
  __syncthreads();
#pragma unroll
  for (int it = 0; it < 16; ++it) {
    const int jj = ty + it * 4;
    dst[(size_t)(c0 + jj) * R + r0 + tx] = f2bf(T[tx][jj] * scale);
  }
}

// ---------------------------------------------------------------------------
// m97-style bf16 GEMM: A[M][K] row-major, Bt[N][K] row-major (= B^T).
// 128x128 tile, BK=64, 4 waves, 16x16x32 MFMA, global_load_lds width 16.
// EPI 0: QKV scatter (q,k as [bh][s][e] bf16; v transposed [bh][e][s] bf16)
// EPI 1: fp32 out + bias
// ---------------------------------------------------------------------------
template <int EPI>
__global__ __launch_bounds__(256)
void gemm_bt(const unsigned short* __restrict__ A,
             const unsigned short* __restrict__ Bt,
             int K, int Ndim,
             unsigned short* __restrict__ q_out,
             unsigned short* __restrict__ k_out,
             unsigned short* __restrict__ vt_out,
             float* __restrict__ o_out,
             const float* __restrict__ bias)
{
  __shared__ unsigned short As[128 * 64];
  __shared__ unsigned short Bs[128 * 64];

  const int tid = threadIdx.x;
  const int w = tid >> 6, lane = tid & 63;
  const int lo = lane & 15, hi = lane >> 4;
  const int wr = w >> 1, wc = w & 1;
  const int row0 = blockIdx.y * 128;
  const int col0 = blockIdx.x * 128;

  f32x4 acc[4][4] = {};

  const int er = w * 32 + (lane >> 3);   // staging row for c=0
  const int ec = (lane & 7) * 8;         // staging col (elements)

  for (int k0 = 0; k0 < K; k0 += 64) {
#pragma unroll
    for (int c = 0; c < 4; ++c) {
      const int rr = er + c * 8;
      gld16(A  + (size_t)(row0 + rr) * K + (k0 + ec), (char*)As + (size_t)(w * 4 + c) * 1024);
      gld16(Bt + (size_t)(col0 + rr) * K + (k0 + ec), (char*)Bs + (size_t)(w * 4 + c) * 1024);
    }
    __syncthreads();
#pragma unroll
    for (int ks = 0; ks < 2; ++ks) {
      bf16x8 af[4], bfr[4];
#pragma unroll
      for (int i = 0; i < 4; ++i)
        af[i] = *(const bf16x8*)&As[(wr * 64 + i * 16 + lo) * 64 + ks * 32 + hi * 8];
#pragma unroll
      for (int j = 0; j < 4; ++j)
        bfr[j] = *(const bf16x8*)&Bs[(wc * 64 + j * 16 + lo) * 64 + ks * 32 + hi * 8];
#pragma unroll
      for (int i = 0; i < 4; ++i)
#pragma unroll
        for (int j = 0; j < 4; ++j)
          acc[i][j] = __builtin_amdgcn_mfma_f32_16x16x32_bf16(af[i], bfr[j], acc[i][j], 0, 0, 0);
    }
    __syncthreads();
  }

#pragma unroll
  for (int i = 0; i < 4; ++i) {
    const int grow = row0 + wr * 64 + i * 16 + hi * 4;  // + r
#pragma unroll
    for (int j = 0; j < 4; ++j) {
      const int gcol = col0 + wc * 64 + j * 16 + lo;
      if (EPI == 0) {
        const int p  = gcol >> 10;
        const int hd = (gcol >> 6) & 15;
        const int e  = gcol & 63;
        const int bb2 = grow >> 11;
        const int s   = grow & 2047;
        const int bh  = bb2 * Hh + hd;
        if (p == 2) {
          const size_t base = ((size_t)bh * HD + e) * Ss + s;  // V^T: s contiguous over r
          ushort4 pk;
          pk.x = f2bf(acc[i][j][0]); pk.y = f2bf(acc[i][j][1]);
          pk.z = f2bf(acc[i][j][2]); pk.w = f2bf(acc[i][j][3]);
          *(ushort4*)&vt_out[base] = pk;
        } else {
          unsigned short* dst = (p == 0) ? q_out : k_out;
          const size_t base = ((size_t)bh * Ss + s) * HD + e;
#pragma unroll
          for (int r = 0; r < 4; ++r) dst[base + (size_t)r * HD] = f2bf(acc[i][j][r]);
        }
      } else {
        const size_t base = (size_t)grow * Ndim + gcol;
        const float bv = bias[gcol];
#pragma unroll
        for (int r = 0; r < 4; ++r) o_out[base + (size_t)r * Ndim] = acc[i][j][r] + bv;
      }
    }
  }
}

// ---------------------------------------------------------------------------
// Flash attention, causal. grid (B*H, S/64 reversed heavy-first), 256 thr
// (4 waves x 16 q-rows of one 64-row q-tile => 4096 waves, ~4/SIMD).
// Q in registers; scores in log2 domain (scale folded into Wq). K/V^T tiles
// XOR-swizzled in LDS, double-buffered, next tile prefetched before compute.
// Defer-max: common path tests only lane-local max (no shfl); full shfl
// reduce + rescale only when some slice exceeds THR=8 (log2). Row sums via
// MFMA-with-ones. P via per-wave swizzled LDS (wave-local, no barrier).
// ---------------------------------------------------------------------------
__global__ __launch_bounds__(256)
void attn_fwd(const unsigned short* __restrict__ qb,
              const unsigned short* __restrict__ kb,
              const unsigned short* __restrict__ vtb,
              unsigned short* __restrict__ ob)
{
  __shared__ unsigned short Ks[2][64 * 64];
  __shared__ unsigned short Vs[2][64 * 64];
  __shared__ unsigned short Ps[4][16 * 64];

  const int qt = 31 - blockIdx.y;        // heavy-first dispatch
  const int bh = blockIdx.x;
  const int bb2 = bh >> 4;
  const int hd = bh & 15;

  const unsigned short* Q  = qb  + (size_t)bh * Ss * HD;
  const unsigned short* Kg = kb  + (size_t)bh * Ss * HD;
  const unsigned short* Vt = vtb + (size_t)bh * HD * Ss;

  const int tid = threadIdx.x;
  const int w = tid >> 6, lane = tid & 63;
  const int lo = lane & 15, hi = lane >> 4;
  const int qrow0 = qt * 64 + w * 16;

  // staging: 8 chunks of 8 rows each; chunk L = c*4 + w; LDS dest linear,
  // global source column pre-swizzled (matches read-side XOR).
  const int srow = lane >> 3;
  const int scol = ((lane & 7) ^ (lane >> 3)) * 8;

#define STAGE(bi, kv)                                                     \
  _Pragma("unroll")                                                       \
  for (int c = 0; c < 2; ++c) {                                           \
    const int L = c * 4 + w;                                              \
    const int rr = L * 8 + srow;                                          \
    gld16(Kg + (size_t)((kv) + rr) * HD + scol,                           \
          (char*)&Ks[bi][0] + L * 1024);                                  \
    gld16(Vt + (size_t)rr * Ss + (kv) + scol,                             \
          (char*)&Vs[bi][0] + L * 1024);                                  \
  }

  const int swl = (lo & 7) << 4;   // read-side XOR (row&7 == lo&7 for frag rows)

  bf16x8 vones;
#pragma unroll
  for (int j = 0; j < 8; ++j) vones[j] = (__bf16)1.0f;

  bf16x8 qf[2];
#pragma unroll
  for (int ks = 0; ks < 2; ++ks)
    qf[ks] = *(const bf16x8*)&Q[(size_t)(qrow0 + lo) * HD + ks * 32 + hi * 8];

  f32x4 oacc[4] = {};
  float m2[4], l2[4];
#pragma unroll
  for (int r = 0; r < 4; ++r) { m2[r] = -INFINITY; l2[r] = 0.f; }

  const int ntiles = qt + 1;

  STAGE(0, 0);
  __syncthreads();

  int cur = 0;
  for (int t = 0; t < ntiles; ++t) {
    if (t + 1 < ntiles) { STAGE(cur ^ 1, (t + 1) * 64); }

    const int kv0 = t * 64;
    const bool diag = (t == qt);

    // S = Q K^T  (log2-domain scores)
    f32x4 sacc[4] = {};
    __builtin_amdgcn_s_setprio(1);
#pragma unroll
    for (int ks = 0; ks < 2; ++ks) {
      bf16x8 kf[4];
#pragma unroll
      for (int nj = 0; nj < 4; ++nj)
        kf[nj] = *(const bf16x8*)((const char*)&Ks[cur][0] +
                 (nj * 16 + lo) * 128 + ((ks * 64 + hi * 16) ^ swl));
#pragma unroll
      for (int nj = 0; nj < 4; ++nj)
        sacc[nj] = __builtin_amdgcn_mfma_f32_16x16x32_bf16(qf[ks], kf[nj], sacc[nj], 0, 0, 0);
    }
    __builtin_amdgcn_s_setprio(0);

    // mask (diag only) + lane-local max; cheap defer-max test (no shfl)
    float lm[4];
    float dmax = -INFINITY;
#pragma unroll
    for (int r = 0; r < 4; ++r) {
      if (diag) {
        const int q = qrow0 + hi * 4 + r;
#pragma unroll
        for (int nj = 0; nj < 4; ++nj) {
          const int kk = kv0 + nj * 16 + lo;
          if (kk > q) sacc[nj][r] = -INFINITY;
        }
      }
      lm[r] = fmaxf(fmaxf(sacc[0][r], sacc[1][r]), fmaxf(sacc[2][r], sacc[3][r]));
      dmax = fmaxf(dmax, lm[r] - m2[r]);
    }
    if (!__all(dmax <= 8.0f)) {
      // exact row max + rescale (first tile and rare outliers only)
#pragma unroll
      for (int r = 0; r < 4; ++r) {
        float rm = lm[r];
#pragma unroll
        for (int d = 1; d < 16; d <<= 1)
          rm = fmaxf(rm, __shfl_xor(rm, d, 64));
        const float mn = fmaxf(m2[r], rm);
        const float rc = __builtin_amdgcn_exp2f(m2[r] - mn);
        m2[r] = mn;
        l2[r] *= rc;
#pragma unroll
        for (int nj = 0; nj < 4; ++nj)
          oacc[nj][r] *= rc;
      }
    }

    // P = exp2(S - m) -> per-wave swizzled LDS (wave-local, no barrier)
    unsigned short* Pw = &Ps[w][0];
#pragma unroll
    for (int nj = 0; nj < 4; ++nj)
#pragma unroll
      for (int r = 0; r < 4; ++r) {
        const float p = __builtin_amdgcn_exp2f(sacc[nj][r] - m2[r]);
        const int prow = hi * 4 + r;
        const int pcb = (nj * 32 + lo * 2) ^ ((prow & 7) << 4);
        *(__bf16*)((char*)Pw + prow * 128 + pcb) = (__bf16)p;
      }

    // O += P V ; row sums via MFMA-with-ones
    f32x4 osum = {};
    __builtin_amdgcn_s_setprio(1);
#pragma unroll
    for (int ks = 0; ks < 2; ++ks) {
      bf16x8 pa, vf[4];
      pa = *(const bf16x8*)((const char*)Pw +
           lo * 128 + ((ks * 64 + hi * 16) ^ swl));
#pragma unroll
      for (int nj = 0; nj < 4; ++nj)
        vf[nj] = *(const bf16x8*)((const char*)&Vs[cur][0] +
                 (nj * 16 + lo) * 128 + ((ks * 64 + hi * 16) ^ swl));
#pragma unroll
      for (int nj = 0; nj < 4; ++nj)
        oacc[nj] = __builtin_amdgcn_mfma_f32_16x16x32_bf16(pa, vf[nj], oacc[nj], 0, 0, 0);
      osum = __builtin_amdgcn_mfma_f32_16x16x32_bf16(pa, vones, osum, 0, 0, 0);
    }
    __builtin_amdgcn_s_setprio(0);
#pragma unroll
    for (int r = 0; r < 4; ++r)
      l2[r] += osum[r];

    __syncthreads();
    cur ^= 1;
  }
#undef STAGE

  // epilogue: ob[b][s][h*64+e] bf16
#pragma unroll
  for (int r = 0; r < 4; ++r) {
    const int s = qrow0 + hi * 4 + r;
    const float il = 1.0f / l2[r];
    const size_t base = ((size_t)bb2 * Ss + s) * Dd + hd * HD;
#pragma unroll
    for (int nj = 0; nj < 4; ++nj)
      ob[base + nj * 16 + lo] = f2bf(oacc[nj][r] * il);
  }
}

// ---------------------------------------------------------------------------
extern "C" void kernel_launch(void* const* d_in, const int* in_sizes, int n_in,
                              void* d_out, int out_size, void* d_ws, size_t ws_size,
                              hipStream_t stream)
{
  const float* x  = (const float*)d_in[0];
  const float* Wq = (const float*)d_in[1];
  const float* Wk = (const float*)d_in[2];
  const float* Wv = (const float*)d_in[3];
  const float* Wo = (const float*)d_in[4];
  const float* bo = (const float*)d_in[5];
  float* out = (float*)d_out;

  char* ws = (char*)d_ws;
  unsigned short* xb    = (unsigned short*)(ws);              //  8,388,608 B
  unsigned short* wqkvT = (unsigned short*)(ws + 8388608);    //  6,291,456 B
  unsigned short* woT   = (unsigned short*)(ws + 14680064);   //  2,097,152 B
  unsigned short* qb    = (unsigned short*)(ws + 16777216);   //  8,388,608 B
  unsigned short* kb    = (unsigned short*)(ws + 25165824);   //  8,388,608 B
  unsigned short* vtb   = (unsigned short*)(ws + 33554432);   //  8,388,608 B
  unsigned short* ob    = (unsigned short*)(ws + 41943040);   //  8,388,608 B (end 48 MiB)

  pack_x_k<<<4096, 256, 0, stream>>>((const float4*)x, xb, 1048576);
  // Wq carries 1/sqrt(HD) * log2(e) so attention scores land in log2 domain
  tconv_k<<<dim3(1, 16, 16), 256, 0, stream>>>(Wq, wqkvT,           1024, 64, 0.18033688011112042f);
  tconv_k<<<dim3(1, 16, 16), 256, 0, stream>>>(Wk, wqkvT + 1048576, 1024, 64, 1.0f);
  tconv_k<<<dim3(1, 16, 16), 256, 0, stream>>>(Wv, wqkvT + 2097152, 1024, 64, 1.0f);
  tconv_k<<<dim3(16, 16, 1), 256, 0, stream>>>(Wo, woT,             1024, 1024, 1.0f);

  // QKV: [4096x1024] @ [1024x3072]
  gemm_bt<0><<<dim3(24, 32), 256, 0, stream>>>(xb, wqkvT, 1024, 3072,
                                               qb, kb, vtb, nullptr, nullptr);
  // attention (4 waves x 16 q-rows per 64-row q-tile; heavy-first)
  attn_fwd<<<dim3(32, 32), 256, 0, stream>>>(qb, kb, vtb, ob);
  // out-proj: [4096x1024] @ [1024x1024] + bo
  gemm_bt<1><<<dim3(8, 32), 256, 0, stream>>>(ob, woT, 1024, 1024,
                                              nullptr, nullptr, nullptr, out, bo);
}

// Round 5
// 131.019 us; speedup vs baseline: 1.7649x; 1.0711x over previous
//
#include <hip/hip_runtime.h>
#include <hip/hip_bf16.h>
#include <cstdint>

#define Hh 16
#define Dd 1024
#define HD 64
#define Bb 2
#define Ss 2048

typedef float f32x4 __attribute__((ext_vector_type(4)));
typedef __bf16 bf16x8 __attribute__((ext_vector_type(8)));

__device__ __forceinline__ unsigned short f2bf(float f) {
  union { float f; unsigned u; } v; v.f = f;
  unsigned r = (v.u + 0x7FFFu + ((v.u >> 16) & 1u)) >> 16;  // RNE, finite inputs
  return (unsigned short)r;
}

__device__ __forceinline__ void gld16(const void* g, void* l) {
  __builtin_amdgcn_global_load_lds(
      (__attribute__((address_space(1))) void*)(g),
      (__attribute__((address_space(3))) void*)(l),
      16, 0, 0);
}

// ---------------------------------------------------------------------------
// Pack x (fp32 -> bf16), vectorized float4 -> ushort4
// ---------------------------------------------------------------------------
__global__ __launch_bounds__(256)
void pack_x_k(const float4* __restrict__ x, unsigned short* __restrict__ xb, int n4) {
  const int i = blockIdx.x * blockDim.x + threadIdx.x;
  if (i >= n4) return;
  const float4 v = x[i];
  ushort4 o;
  o.x = f2bf(v.x); o.y = f2bf(v.y); o.z = f2bf(v.z); o.w = f2bf(v.w);
  *(ushort4*)&xb[(size_t)i * 4] = o;
}

// ---------------------------------------------------------------------------
// Batched transpose + scale + fp32->bf16: out[m][c][r] = in[m][r][c] * scale
// grid: (C/64, R/64, nmat), block 256
// ---------------------------------------------------------------------------
__global__ __launch_bounds__(256)
void tconv_k(const float* __restrict__ in, unsigned short* __restrict__ out,
             int R, int C, float scale) {
  __shared__ float T[64][65];
  const int m = blockIdx.z;
  const float* src = in + (size_t)m * R * C;
  unsigned short* dst = out + (size_t)m * R * C;
  const int c0 = blockIdx.x * 64, r0 = blockIdx.y * 64;
  const int tx = threadIdx.x & 63, ty = threadIdx.x >> 6;
#pragma unroll
  for (int it = 0; it < 16; ++it) {
    const int i = ty + it * 4;
    T[i][tx] = src[(size_t)(r0 + i) * C + c0 + tx];
  }
  __syncthreads();
#pragma unroll
  for (int it = 0; it < 16; ++it) {
    const int jj = ty + it * 4;
    dst[(size_t)(c0 + jj) * R + r0 + tx] = f2bf(T[tx][jj] * scale);
  }
}

// ---------------------------------------------------------------------------
// bf16 GEMM, 128x128 tile, BK=64, 4 waves, 2-phase double-buffered LDS
// (prefetch next K-tile before compute, one barrier/step), T2 XOR-swizzle
// (pre-swizzled global source col + swizzled ds_read), 16x16x32 MFMA.
// EPI 0: q/k — TRANSPOSED acc (mfma operand swap) -> ushort4 scatter [bh][s][e]
// EPI 1: v   — normal acc -> ushort4 V^T [bh][e][s]
// EPI 2: out-proj — TRANSPOSED acc -> float4 +bias, row-major [m][n]
// ---------------------------------------------------------------------------
template <int EPI>
__global__ __launch_bounds__(256)
void gemm_bt(const unsigned short* __restrict__ A,
             const unsigned short* __restrict__ Bt,
             int K, int Ndim,
             unsigned short* __restrict__ q_out,
             unsigned short* __restrict__ k_out,
             unsigned short* __restrict__ vt_out,
             float* __restrict__ o_out,
             const float* __restrict__ bias)
{
  __shared__ unsigned short As[2][128 * 64];
  __shared__ unsigned short Bs[2][128 * 64];

  const int tid = threadIdx.x;
  const int w = tid >> 6, lane = tid & 63;
  const int lo = lane & 15, hi = lane >> 4;
  const int wr = w >> 1, wc = w & 1;
  const int row0 = blockIdx.y * 128;
  const int col0 = blockIdx.x * 128;

  f32x4 acc[4][4] = {};

  const int srow = w * 32 + (lane >> 3);            // staging row (+ c*8)
  const int scol = ((lane & 7) ^ (lane >> 3)) * 8;  // pre-swizzled source col
  const int swl  = (lo & 7) << 4;                   // read-side XOR

#define GSTAGE(bi, k0)                                                    \
  _Pragma("unroll")                                                       \
  for (int c = 0; c < 4; ++c) {                                           \
    const int rr = srow + c * 8;                                          \
    gld16(A  + (size_t)(row0 + rr) * K + ((k0) + scol),                   \
          (char*)&As[bi][0] + (w * 4 + c) * 1024);                        \
    gld16(Bt + (size_t)(col0 + rr) * K + ((k0) + scol),                   \
          (char*)&Bs[bi][0] + (w * 4 + c) * 1024);                        \
  }

  GSTAGE(0, 0);
  __syncthreads();

  const int nst = K >> 6;
  int cur = 0;
  for (int t = 0; t < nst; ++t) {
    if (t + 1 < nst) { GSTAGE(cur ^ 1, (t + 1) * 64); }
#pragma unroll
    for (int ks = 0; ks < 2; ++ks) {
      bf16x8 af[4], bfr[4];
#pragma unroll
      for (int i = 0; i < 4; ++i)
        af[i] = *(const bf16x8*)((const char*)&As[cur][0] +
                 (wr * 64 + i * 16 + lo) * 128 + ((ks * 64 + hi * 16) ^ swl));
#pragma unroll
      for (int j = 0; j < 4; ++j)
        bfr[j] = *(const bf16x8*)((const char*)&Bs[cur][0] +
                 (wc * 64 + j * 16 + lo) * 128 + ((ks * 64 + hi * 16) ^ swl));
      __builtin_amdgcn_s_setprio(1);
#pragma unroll
      for (int i = 0; i < 4; ++i)
#pragma unroll
        for (int j = 0; j < 4; ++j) {
          if (EPI == 1)
            acc[i][j] = __builtin_amdgcn_mfma_f32_16x16x32_bf16(af[i], bfr[j], acc[i][j], 0, 0, 0);
          else  // transposed output: D^T (rows = n)
            acc[i][j] = __builtin_amdgcn_mfma_f32_16x16x32_bf16(bfr[j], af[i], acc[i][j], 0, 0, 0);
        }
      __builtin_amdgcn_s_setprio(0);
    }
    __syncthreads();
    cur ^= 1;
  }

#pragma unroll
  for (int i = 0; i < 4; ++i) {
#pragma unroll
    for (int j = 0; j < 4; ++j) {
      if (EPI == 1) {
        // normal acc: lane holds 4 consecutive s at fixed e (V^T friendly)
        const int grow = row0 + wr * 64 + i * 16 + hi * 4;   // s (+r)
        const int gcol = col0 + wc * 64 + j * 16 + lo;       // 0..1023 in v
        const int hd = gcol >> 6, e = gcol & 63;
        const int bb2 = grow >> 11, s = grow & 2047;
        ushort4 pk;
        pk.x = f2bf(acc[i][j][0]); pk.y = f2bf(acc[i][j][1]);
        pk.z = f2bf(acc[i][j][2]); pk.w = f2bf(acc[i][j][3]);
        *(ushort4*)&vt_out[((size_t)(bb2 * Hh + hd) * HD + e) * Ss + s] = pk;
      } else {
        // transposed acc: lane holds 4 consecutive n at fixed row m
        const int m  = row0 + wr * 64 + i * 16 + lo;
        const int n0 = col0 + wc * 64 + j * 16 + hi * 4;
        if (EPI == 0) {
          const int p = n0 >> 10;
          const int hd = (n0 >> 6) & 15;
          const int e = n0 & 63;
          const int bb2 = m >> 11, s = m & 2047;
          unsigned short* dst = (p == 0) ? q_out : k_out;
          ushort4 pk;
          pk.x = f2bf(acc[i][j][0]); pk.y = f2bf(acc[i][j][1]);
          pk.z = f2bf(acc[i][j][2]); pk.w = f2bf(acc[i][j][3]);
          *(ushort4*)&dst[((size_t)(bb2 * Hh + hd) * Ss + s) * HD + e] = pk;
        } else {
          const float4 bv = *(const float4*)&bias[n0];
          float4 o;
          o.x = acc[i][j][0] + bv.x; o.y = acc[i][j][1] + bv.y;
          o.z = acc[i][j][2] + bv.z; o.w = acc[i][j][3] + bv.w;
          *(float4*)&o_out[(size_t)m * Ndim + n0] = o;
        }
      }
    }
  }
#undef GSTAGE
}

// ---------------------------------------------------------------------------
// Flash attention, causal. grid (B*H, S/64 reversed heavy-first), 256 thr
// (4 waves x 16 q-rows of one 64-row q-tile => 4096 waves, ~4/SIMD).
// Q in registers; scores in log2 domain (scale folded into Wq). K/V^T tiles
// XOR-swizzled in LDS, double-buffered, next tile prefetched before compute.
// Defer-max: common path tests only lane-local max (no shfl); full shfl
// reduce + rescale only when some slice exceeds THR=8 (log2). Row sums via
// MFMA-with-ones. P via per-wave swizzled LDS (wave-local, no barrier).
// ---------------------------------------------------------------------------
__global__ __launch_bounds__(256)
void attn_fwd(const unsigned short* __restrict__ qb,
              const unsigned short* __restrict__ kb,
              const unsigned short* __restrict__ vtb,
              unsigned short* __restrict__ ob)
{
  __shared__ unsigned short Ks[2][64 * 64];
  __shared__ unsigned short Vs[2][64 * 64];
  __shared__ unsigned short Ps[4][16 * 64];

  const int qt = 31 - blockIdx.y;        // heavy-first dispatch
  const int bh = blockIdx.x;
  const int bb2 = bh >> 4;
  const int hd = bh & 15;

  const unsigned short* Q  = qb  + (size_t)bh * Ss * HD;
  const unsigned short* Kg = kb  + (size_t)bh * Ss * HD;
  const unsigned short* Vt = vtb + (size_t)bh * HD * Ss;

  const int tid = threadIdx.x;
  const int w = tid >> 6, lane = tid & 63;
  const int lo = lane & 15, hi = lane >> 4;
  const int qrow0 = qt * 64 + w * 16;

  // staging: 8 chunks of 8 rows each; chunk L = c*4 + w; LDS dest linear,
  // global source column pre-swizzled (matches read-side XOR).
  const int srow = lane >> 3;
  const int scol = ((lane & 7) ^ (lane >> 3)) * 8;

#define STAGE(bi, kv)                                                     \
  _Pragma("unroll")                                                       \
  for (int c = 0; c < 2; ++c) {                                           \
    const int L = c * 4 + w;                                              \
    const int rr = L * 8 + srow;                                          \
    gld16(Kg + (size_t)((kv) + rr) * HD + scol,                           \
          (char*)&Ks[bi][0] + L * 1024);                                  \
    gld16(Vt + (size_t)rr * Ss + (kv) + scol,                             \
          (char*)&Vs[bi][0] + L * 1024);                                  \
  }

  const int swl = (lo & 7) << 4;   // read-side XOR (row&7 == lo&7 for frag rows)

  bf16x8 vones;
#pragma unroll
  for (int j = 0; j < 8; ++j) vones[j] = (__bf16)1.0f;

  bf16x8 qf[2];
#pragma unroll
  for (int ks = 0; ks < 2; ++ks)
    qf[ks] = *(const bf16x8*)&Q[(size_t)(qrow0 + lo) * HD + ks * 32 + hi * 8];

  f32x4 oacc[4] = {};
  float m2[4], l2[4];
#pragma unroll
  for (int r = 0; r < 4; ++r) { m2[r] = -INFINITY; l2[r] = 0.f; }

  const int ntiles = qt + 1;

  STAGE(0, 0);
  __syncthreads();

  int cur = 0;
  for (int t = 0; t < ntiles; ++t) {
    if (t + 1 < ntiles) { STAGE(cur ^ 1, (t + 1) * 64); }

    const int kv0 = t * 64;
    const bool diag = (t == qt);

    // S = Q K^T  (log2-domain scores)
    f32x4 sacc[4] = {};
    __builtin_amdgcn_s_setprio(1);
#pragma unroll
    for (int ks = 0; ks < 2; ++ks) {
      bf16x8 kf[4];
#pragma unroll
      for (int nj = 0; nj < 4; ++nj)
        kf[nj] = *(const bf16x8*)((const char*)&Ks[cur][0] +
                 (nj * 16 + lo) * 128 + ((ks * 64 + hi * 16) ^ swl));
#pragma unroll
      for (int nj = 0; nj < 4; ++nj)
        sacc[nj] = __builtin_amdgcn_mfma_f32_16x16x32_bf16(qf[ks], kf[nj], sacc[nj], 0, 0, 0);
    }
    __builtin_amdgcn_s_setprio(0);

    // mask (diag only) + lane-local max; cheap defer-max test (no shfl)
    float lm[4];
    float dmax = -INFINITY;
#pragma unroll
    for (int r = 0; r < 4; ++r) {
      if (diag) {
        const int q = qrow0 + hi * 4 + r;
#pragma unroll
        for (int nj = 0; nj < 4; ++nj) {
          const int kk = kv0 + nj * 16 + lo;
          if (kk > q) sacc[nj][r] = -INFINITY;
        }
      }
      lm[r] = fmaxf(fmaxf(sacc[0][r], sacc[1][r]), fmaxf(sacc[2][r], sacc[3][r]));
      dmax = fmaxf(dmax, lm[r] - m2[r]);
    }
    if (!__all(dmax <= 8.0f)) {
      // exact row max + rescale (first tile and rare outliers only)
#pragma unroll
      for (int r = 0; r < 4; ++r) {
        float rm = lm[r];
#pragma unroll
        for (int d = 1; d < 16; d <<= 1)
          rm = fmaxf(rm, __shfl_xor(rm, d, 64));
        const float mn = fmaxf(m2[r], rm);
        const float rc = __builtin_amdgcn_exp2f(m2[r] - mn);
        m2[r] = mn;
        l2[r] *= rc;
#pragma unroll
        for (int nj = 0; nj < 4; ++nj)
          oacc[nj][r] *= rc;
      }
    }

    // P = exp2(S - m) -> per-wave swizzled LDS (wave-local, no barrier)
    unsigned short* Pw = &Ps[w][0];
#pragma unroll
    for (int nj = 0; nj < 4; ++nj)
#pragma unroll
      for (int r = 0; r < 4; ++r) {
        const float p = __builtin_amdgcn_exp2f(sacc[nj][r] - m2[r]);
        const int prow = hi * 4 + r;
        const int pcb = (nj * 32 + lo * 2) ^ ((prow & 7) << 4);
        *(__bf16*)((char*)Pw + prow * 128 + pcb) = (__bf16)p;
      }

    // O += P V ; row sums via MFMA-with-ones
    f32x4 osum = {};
    __builtin_amdgcn_s_setprio(1);
#pragma unroll
    for (int ks = 0; ks < 2; ++ks) {
      bf16x8 pa, vf[4];
      pa = *(const bf16x8*)((const char*)Pw +
           lo * 128 + ((ks * 64 + hi * 16) ^ swl));
#pragma unroll
      for (int nj = 0; nj < 4; ++nj)
        vf[nj] = *(const bf16x8*)((const char*)&Vs[cur][0] +
                 (nj * 16 + lo) * 128 + ((ks * 64 + hi * 16) ^ swl));
#pragma unroll
      for (int nj = 0; nj < 4; ++nj)
        oacc[nj] = __builtin_amdgcn_mfma_f32_16x16x32_bf16(pa, vf[nj], oacc[nj], 0, 0, 0);
      osum = __builtin_amdgcn_mfma_f32_16x16x32_bf16(pa, vones, osum, 0, 0, 0);
    }
    __builtin_amdgcn_s_setprio(0);
#pragma unroll
    for (int r = 0; r < 4; ++r)
      l2[r] += osum[r];

    __syncthreads();
    cur ^= 1;
  }
#undef STAGE

  // epilogue: ob[b][s][h*64+e] bf16
#pragma unroll
  for (int r = 0; r < 4; ++r) {
    const int s = qrow0 + hi * 4 + r;
    const float il = 1.0f / l2[r];
    const size_t base = ((size_t)bb2 * Ss + s) * Dd + hd * HD;
#pragma unroll
    for (int nj = 0; nj < 4; ++nj)
      ob[base + nj * 16 + lo] = f2bf(oacc[nj][r] * il);
  }
}

// ---------------------------------------------------------------------------
extern "C" void kernel_launch(void* const* d_in, const int* in_sizes, int n_in,
                              void* d_out, int out_size, void* d_ws, size_t ws_size,
                              hipStream_t stream)
{
  const float* x  = (const float*)d_in[0];
  const float* Wq = (const float*)d_in[1];
  const float* Wk = (const float*)d_in[2];
  const float* Wv = (const float*)d_in[3];
  const float* Wo = (const float*)d_in[4];
  const float* bo = (const float*)d_in[5];
  float* out = (float*)d_out;

  char* ws = (char*)d_ws;
  unsigned short* xb    = (unsigned short*)(ws);              //  8,388,608 B
  unsigned short* wqkvT = (unsigned short*)(ws + 8388608);    //  6,291,456 B
  unsigned short* woT   = (unsigned short*)(ws + 14680064);   //  2,097,152 B
  unsigned short* qb    = (unsigned short*)(ws + 16777216);   //  8,388,608 B
  unsigned short* kb    = (unsigned short*)(ws + 25165824);   //  8,388,608 B
  unsigned short* vtb   = (unsigned short*)(ws + 33554432);   //  8,388,608 B
  unsigned short* ob    = (unsigned short*)(ws + 41943040);   //  8,388,608 B (end 48 MiB)

  pack_x_k<<<4096, 256, 0, stream>>>((const float4*)x, xb, 1048576);
  // Wq carries 1/sqrt(HD) * log2(e) so attention scores land in log2 domain
  tconv_k<<<dim3(1, 16, 16), 256, 0, stream>>>(Wq, wqkvT,           1024, 64, 0.18033688011112042f);
  tconv_k<<<dim3(1, 16, 16), 256, 0, stream>>>(Wk, wqkvT + 1048576, 1024, 64, 1.0f);
  tconv_k<<<dim3(1, 16, 16), 256, 0, stream>>>(Wv, wqkvT + 2097152, 1024, 64, 1.0f);
  tconv_k<<<dim3(16, 16, 1), 256, 0, stream>>>(Wo, woT,             1024, 1024, 1.0f);

  // q/k projection: [4096x1024] @ [1024x2048] (transposed-output epilogue)
  gemm_bt<0><<<dim3(16, 32), 256, 0, stream>>>(xb, wqkvT, 1024, 0,
                                               qb, kb, nullptr, nullptr, nullptr);
  // v projection: [4096x1024] @ [1024x1024] -> V^T
  gemm_bt<1><<<dim3(8, 32), 256, 0, stream>>>(xb, wqkvT + 2097152, 1024, 0,
                                              nullptr, nullptr, vtb, nullptr, nullptr);
  // attention (4 waves x 16 q-rows per 64-row q-tile; heavy-first)
  attn_fwd<<<dim3(32, 32), 256, 0, stream>>>(qb, kb, vtb, ob);
  // out-proj: [4096x1024] @ [1024x1024] + bo (transposed-output epilogue)
  gemm_bt<2><<<dim3(8, 32), 256, 0, stream>>>(ob, woT, 1024, 1024,
                                              nullptr, nullptr, nullptr, out, bo);
}